// Round 8
// baseline (58.851 us; speedup 1.0000x reference)
//
#include <hip/hip_runtime.h>
#include <stdint.h>

#define NBOX 8192

// ws layout: float4 sbox[8192] (128 KB) then uint32_t flags[256] (1 KB).
// DECOMPOSITION ROUND: R3 pipeline (rank_u64 + chunked suppress + write, the
// proven 36.4 us config) + an idempotent SECOND suppress (R7 N-body) OR-ing
// the same flags. Delta vs 36.4 measures the N-body kernel's true cost.

// ---------------------------------------------------------------------------
// Kernel 1: stable rank by (desc score, asc index) — EXACT R3 copy.
// key = (~score_bits << 32) | index  -> ascending u64 == desired order.
// ---------------------------------------------------------------------------
__global__ __launch_bounds__(256) void nms_rank_kernel(
    const float4* __restrict__ bbox, const float* __restrict__ score,
    float4* __restrict__ sbox, uint32_t* __restrict__ flags)
{
    __shared__ uint64_t keys[NBOX];          // 64 KB
    const int t = threadIdx.x;
    if (blockIdx.x == 0) flags[t] = 0;       // 256 words

    #pragma unroll
    for (int s = 0; s < NBOX / 256; ++s) {
        int i = t + s * 256;
        uint32_t b = __float_as_uint(score[i]);   // scores in [0,1): bits monotone
        keys[i] = ((uint64_t)(b ^ 0xFFFFFFFFu) << 32) | (uint32_t)i;
    }
    __syncthreads();

    const int e = blockIdx.x * 16 + (t >> 4);
    const int p = t & 15;
    const uint64_t myk = keys[e];
    int cnt = 0;
    #pragma unroll 8
    for (int s = 0; s < NBOX / 16; ++s)
        cnt += (keys[s * 16 + p] < myk) ? 1 : 0;

    cnt += __shfl_down(cnt, 8, 16);
    cnt += __shfl_down(cnt, 4, 16);
    cnt += __shfl_down(cnt, 2, 16);
    cnt += __shfl_down(cnt, 1, 16);

    if (p == 0) sbox[cnt] = bbox[e];
}

// ---------------------------------------------------------------------------
// Kernel 2: chunked suppression — EXACT R3 copy (part of the 36.4 us config).
// ---------------------------------------------------------------------------
__global__ __launch_bounds__(256) void nms_suppress_kernel(
    const float4* __restrict__ sbox, uint32_t* __restrict__ flags)
{
    const int w    = (int)(threadIdx.x >> 6);
    const int lane = (int)(threadIdx.x & 63);
    const int is   = (int)(blockIdx.x >> 8);
    const int jg   = ((int)(blockIdx.x & 255)) * 4 + w;
    const int j0   = jg * 8;
    const int s0   = is * 512;
    if (s0 >= j0 + 7) return;

    int nfull = (j0 - s0) >> 6;
    if (nfull < 0) nfull = 0;
    if (nfull > 8) nfull = 8;
    const int pc = nfull;
    const bool partial = (pc < 8) && (s0 + pc * 64 < j0 + 7);

    float jy1[8], jx1[8], jy2[8], jx2[8], ja[8], tk[8];
    #pragma unroll
    for (int k = 0; k < 8; ++k) {
        float4 b = sbox[j0 + k];
        jy1[k] = b.x; jx1[k] = b.y; jy2[k] = b.z; jx2[k] = b.w;
        ja[k] = (b.z - b.x) * (b.w - b.y);
        tk[k] = 0.4110f * ja[k];
    }

    uint32_t hit = 0;
    float4 cur = sbox[s0 + lane];

    for (int c = 0; c < nfull; ++c) {
        float4 nxt = sbox[s0 + (c + 1) * 64 + lane];

        const float iy1 = cur.x, ix1 = cur.y, iy2 = cur.z, ix2 = cur.w;
        const float ia  = (iy2 - iy1) * (ix2 - ix1);
        const float tia = 0.4110f * ia;

        int cand = 0;
        #pragma unroll
        for (int k = 0; k < 8; ++k) {
            float ty1 = fmaxf(iy1, jy1[k]);
            float tx1 = fmaxf(ix1, jx1[k]);
            float ty2 = fminf(iy2, jy2[k]);
            float tx2 = fminf(ix2, jx2[k]);
            float ih = fmaxf(ty2 - ty1, 0.0f);
            float iw = fmaxf(tx2 - tx1, 0.0f);
            float inter = ih * iw;
            cand |= __any(inter > tia + tk[k]);
        }
        if (cand) {
            #pragma unroll
            for (int k = 0; k < 8; ++k) {
                float ty1 = fmaxf(iy1, jy1[k]);
                float tx1 = fmaxf(ix1, jx1[k]);
                float ty2 = fminf(iy2, jy2[k]);
                float tx2 = fminf(ix2, jx2[k]);
                float ih = fmaxf(ty2 - ty1, 0.0f);
                float iw = fmaxf(tx2 - tx1, 0.0f);
                float inter = ih * iw;
                float s  = ia + ja[k];
                float un = s - inter;
                float iou = inter / fmaxf(un, 1e-9f);
                if (iou > 0.7f) hit |= (1u << k);
            }
        }
        cur = nxt;
    }

    if (partial) {
        const int i = s0 + pc * 64 + lane;
        const float iy1 = cur.x, ix1 = cur.y, iy2 = cur.z, ix2 = cur.w;
        const float ia  = (iy2 - iy1) * (ix2 - ix1);
        const float tia = 0.4110f * ia;

        int cand = 0;
        #pragma unroll
        for (int k = 0; k < 8; ++k) {
            float ty1 = fmaxf(iy1, jy1[k]);
            float tx1 = fmaxf(ix1, jx1[k]);
            float ty2 = fminf(iy2, jy2[k]);
            float tx2 = fminf(ix2, jx2[k]);
            float ih = fmaxf(ty2 - ty1, 0.0f);
            float iw = fmaxf(tx2 - tx1, 0.0f);
            float inter = ih * iw;
            cand |= __any((i < j0 + k) & (inter > tia + tk[k]));
        }
        if (cand) {
            #pragma unroll
            for (int k = 0; k < 8; ++k) {
                float ty1 = fmaxf(iy1, jy1[k]);
                float tx1 = fmaxf(ix1, jx1[k]);
                float ty2 = fminf(iy2, jy2[k]);
                float tx2 = fminf(ix2, jx2[k]);
                float ih = fmaxf(ty2 - ty1, 0.0f);
                float iw = fmaxf(tx2 - tx1, 0.0f);
                float inter = ih * iw;
                float s  = ia + ja[k];
                float un = s - inter;
                float iou = inter / fmaxf(un, 1e-9f);
                if ((i < j0 + k) & (iou > 0.7f)) hit |= (1u << k);
            }
        }
    }

    uint32_t byte = 0;
    #pragma unroll
    for (int k = 0; k < 8; ++k)
        if (__any(hit & (1u << k))) byte |= (1u << k);
    if (lane == 0 && byte)
        atomicOr(&flags[jg >> 2], byte << ((jg & 3) * 8));
    // bit index within word jg>>2 == j>>5 is ((j>>3)&3)*8 + (j&7) == j&31:
    // identical layout to the N-body kernel below -> idempotent OR.
}

// ---------------------------------------------------------------------------
// Kernel 2b: N-body suppression — EXACT R7 copy, run as an idempotent second
// pass over the same flags (measures its true cost by Delta vs 36.4 us).
// ---------------------------------------------------------------------------
__device__ __forceinline__ bool iou_hit(float4 bi, float ia,
                                        float jy1, float jx1, float jy2,
                                        float jx2, float ja) {
    const double MD = (double)0.7f + 0x1.0p-25;
    float ty1 = fmaxf(bi.x, jy1);
    float tx1 = fmaxf(bi.y, jx1);
    float ty2 = fminf(bi.z, jy2);
    float tx2 = fminf(bi.w, jx2);
    float ih = fmaxf(__fsub_rn(ty2, ty1), 0.0f);
    float iw = fmaxf(__fsub_rn(tx2, tx1), 0.0f);
    float inter = __fmul_rn(ih, iw);
    float s  = __fadd_rn(ia, ja);
    float un = __fsub_rn(s, inter);
    return (double)inter >= MD * (double)un;
}

__global__ __launch_bounds__(256, 4) void nms_suppress_nbody(
    const float4* __restrict__ sbox, uint32_t* __restrict__ flags)
{
    __shared__ float4 LB[128];
    __shared__ float  LA[128];
    const int tid = threadIdx.x;
    const int b = (int)blockIdx.x;

    int jb = (int)((sqrtf(4.0f * (float)b + 1.0f) - 1.0f) * 0.5f);
    while ((jb + 1) * (jb + 2) <= b) ++jb;
    while (jb * (jb + 1) > b) --jb;
    const int t = b - jb * (jb + 1);
    const int ibase = t * 128;
    const int j = jb * 256 + tid;

    if (tid < 128) {
        float4 bx = sbox[ibase + tid];
        LB[tid] = bx;
        LA[tid] = __fmul_rn(__fsub_rn(bx.z, bx.x), __fsub_rn(bx.w, bx.y));
    }
    float4 bj = sbox[j];
    const float jy1 = bj.x, jx1 = bj.y, jy2 = bj.z, jx2 = bj.w;
    const float ja = __fmul_rn(__fsub_rn(bj.z, bj.x), __fsub_rn(bj.w, bj.y));
    __syncthreads();

    bool supp = false;
    if (t < 2 * jb) {
        #pragma unroll 4
        for (int ii = 0; ii < 128; ++ii)
            supp |= iou_hit(LB[ii], LA[ii], jy1, jx1, jy2, jx2, ja);
    } else {
        #pragma unroll 4
        for (int ii = 0; ii < 128; ++ii) {
            bool ok = (ibase + ii) < j;
            supp |= ok & iou_hit(LB[ii], LA[ii], jy1, jx1, jy2, jx2, ja);
        }
    }

    if (supp) atomicOr(&flags[j >> 5], 1u << (j & 31));
}

// ---------------------------------------------------------------------------
// Kernel 3: masked float4 write — EXACT R3 copy.
// ---------------------------------------------------------------------------
__global__ __launch_bounds__(256) void nms_write_kernel(
    const float4* __restrict__ sbox, const uint32_t* __restrict__ flags,
    float4* __restrict__ out)
{
    int j = blockIdx.x * 256 + threadIdx.x;
    bool sup = (flags[j >> 5] >> (j & 31)) & 1u;
    float4 v = sbox[j];
    if (sup) { v.x = 0.0f; v.y = 0.0f; v.z = 0.0f; v.w = 0.0f; }
    out[j] = v;
}

extern "C" void kernel_launch(void* const* d_in, const int* in_sizes, int n_in,
                              void* d_out, int out_size, void* d_ws, size_t ws_size,
                              hipStream_t stream) {
    const float4* bbox  = (const float4*)d_in[0];   // (8192,4) f32
    const float*  score = (const float*)d_in[1];    // (8192,)  f32
    float4* out = (float4*)d_out;                   // (8192,4) f32
    float4* sbox = (float4*)d_ws;                   // 128 KB
    uint32_t* flags = (uint32_t*)((char*)d_ws + NBOX * 16);  // 1 KB

    hipLaunchKernelGGL(nms_rank_kernel, dim3(NBOX / 16), dim3(256), 0, stream,
                       bbox, score, sbox, flags);
    hipLaunchKernelGGL(nms_suppress_kernel, dim3(4096), dim3(256), 0, stream,
                       sbox, flags);
    hipLaunchKernelGGL(nms_suppress_nbody, dim3(1056), dim3(256), 0, stream,
                       sbox, flags);
    hipLaunchKernelGGL(nms_write_kernel, dim3(NBOX / 256), dim3(256), 0, stream,
                       sbox, flags, out);
}

// Round 9
// 35.599 us; speedup vs baseline: 1.6531x; 1.6531x over previous
//
#include <hip/hip_runtime.h>
#include <stdint.h>

#define NBOX 8192

// ws layout: float4 sbox[8192] (128 KB) then uint32_t flags[256] (1 KB).

// ---------------------------------------------------------------------------
// Kernel 1: stable rank by (desc score, asc index) — proven R3 version.
// key = (~score_bits << 32) | index  -> ascending u64 == desired order.
// ---------------------------------------------------------------------------
__global__ __launch_bounds__(256) void nms_rank_kernel(
    const float4* __restrict__ bbox, const float* __restrict__ score,
    float4* __restrict__ sbox, uint32_t* __restrict__ flags)
{
    __shared__ uint64_t keys[NBOX];          // 64 KB
    const int t = threadIdx.x;
    if (blockIdx.x == 0) flags[t] = 0;       // 256 words

    #pragma unroll
    for (int s = 0; s < NBOX / 256; ++s) {
        int i = t + s * 256;
        uint32_t b = __float_as_uint(score[i]);   // scores in [0,1): bits monotone
        keys[i] = ((uint64_t)(b ^ 0xFFFFFFFFu) << 32) | (uint32_t)i;
    }
    __syncthreads();

    const int e = blockIdx.x * 16 + (t >> 4);
    const int p = t & 15;
    const uint64_t myk = keys[e];
    int cnt = 0;
    #pragma unroll 8
    for (int s = 0; s < NBOX / 16; ++s)
        cnt += (keys[s * 16 + p] < myk) ? 1 : 0;

    cnt += __shfl_down(cnt, 8, 16);
    cnt += __shfl_down(cnt, 4, 16);
    cnt += __shfl_down(cnt, 2, 16);
    cnt += __shfl_down(cnt, 1, 16);

    if (p == 0) sbox[cnt] = bbox[e];
}

// ---------------------------------------------------------------------------
// Kernel 2: T=4 tile suppression. Block = one 32-box i-tile (LDS) x 1024
// j-rows (4 per thread, stride 256). Hot loop: 13 VALU/pair, branch-free,
// identical for full and diagonal tiles; per-pair candidate bits accumulate
// into a 32-bit mask (bit k <-> tile slot k, via descending ii). Diagonal
// masking folded in afterwards as candm &= validm. Rare exact path walks set
// bits only: IEEE f32 reference math (incl. division), __f*_rn to block
// fma-contraction. Prefilter inter > 0.4110*ia + 0.4110*ja is conservative:
// true hit => inter > 0.7/1.7*(ai+aj)*(1-eps) = 0.41176*(1-eps)*(ai+aj);
// margin 1.8e-3 >> all f32 rounding; union >= 256 so the 1e-9 clamp is
// identity. Triangular grid: blocks before jb = 16*jb*(jb+1); 1152 total.
// ---------------------------------------------------------------------------
__global__ __launch_bounds__(256, 4) void nms_suppress_kernel(
    const float4* __restrict__ sbox, uint32_t* __restrict__ flags)
{
    __shared__ float4 LB[32];                // i-tile boxes (512 B)
    __shared__ float  LTH[32];               // 0.4110f * area_i

    const int tid = threadIdx.x;
    const int b = (int)blockIdx.x;

    int jb = (int)(sqrtf((float)b * 0.0625f + 0.25f) - 0.5f);
    while (16 * (jb + 1) * (jb + 2) <= b) ++jb;
    while (16 * jb * (jb + 1) > b) --jb;
    const int it = b - 16 * jb * (jb + 1);   // 0 .. 32*jb+31
    const int ibase = it * 32;               // <= 8160
    const int jbase = jb * 1024;

    if (tid < 32) {
        float4 bx = sbox[ibase + tid];
        LB[tid] = bx;
        LTH[tid] = 0.4110f * ((bx.z - bx.x) * (bx.w - bx.y));
    }

    const float4 bj0 = sbox[jbase + tid];
    const float4 bj1 = sbox[jbase + 256 + tid];
    const float4 bj2 = sbox[jbase + 512 + tid];
    const float4 bj3 = sbox[jbase + 768 + tid];
    const float tk0 = 0.4110f * ((bj0.z - bj0.x) * (bj0.w - bj0.y));
    const float tk1 = 0.4110f * ((bj1.z - bj1.x) * (bj1.w - bj1.y));
    const float tk2 = 0.4110f * ((bj2.z - bj2.x) * (bj2.w - bj2.y));
    const float tk3 = 0.4110f * ((bj3.z - bj3.x) * (bj3.w - bj3.y));
    __syncthreads();

    uint32_t c0 = 0, c1 = 0, c2 = 0, c3 = 0;
    #pragma unroll 8
    for (int ii = 31; ii >= 0; --ii) {       // descending: bit k <-> slot k
        const float4 bi = LB[ii];
        const float tia = LTH[ii];
        {
            float ty1 = fmaxf(bi.x, bj0.x), tx1 = fmaxf(bi.y, bj0.y);
            float ty2 = fminf(bi.z, bj0.z), tx2 = fminf(bi.w, bj0.w);
            float ih = fmaxf(ty2 - ty1, 0.0f), iw = fmaxf(tx2 - tx1, 0.0f);
            c0 = (c0 << 1) | ((ih * iw > tia + tk0) ? 1u : 0u);
        }
        {
            float ty1 = fmaxf(bi.x, bj1.x), tx1 = fmaxf(bi.y, bj1.y);
            float ty2 = fminf(bi.z, bj1.z), tx2 = fminf(bi.w, bj1.w);
            float ih = fmaxf(ty2 - ty1, 0.0f), iw = fmaxf(tx2 - tx1, 0.0f);
            c1 = (c1 << 1) | ((ih * iw > tia + tk1) ? 1u : 0u);
        }
        {
            float ty1 = fmaxf(bi.x, bj2.x), tx1 = fmaxf(bi.y, bj2.y);
            float ty2 = fminf(bi.z, bj2.z), tx2 = fminf(bi.w, bj2.w);
            float ih = fmaxf(ty2 - ty1, 0.0f), iw = fmaxf(tx2 - tx1, 0.0f);
            c2 = (c2 << 1) | ((ih * iw > tia + tk2) ? 1u : 0u);
        }
        {
            float ty1 = fmaxf(bi.x, bj3.x), tx1 = fmaxf(bi.y, bj3.y);
            float ty2 = fminf(bi.z, bj3.z), tx2 = fminf(bi.w, bj3.w);
            float ih = fmaxf(ty2 - ty1, 0.0f), iw = fmaxf(tx2 - tx1, 0.0f);
            c3 = (c3 << 1) | ((ih * iw > tia + tk3) ? 1u : 0u);
        }
    }

    // diagonal masking: valid slots are ii < j - ibase (full tiles -> ~0u)
    {
        int d0 = jbase + tid - ibase;
        int d1 = d0 + 256, d2 = d0 + 512, d3 = d0 + 768;
        c0 &= (d0 <= 0) ? 0u : ((d0 >= 32) ? ~0u : ((1u << d0) - 1u));
        c1 &= (d1 <= 0) ? 0u : ((d1 >= 32) ? ~0u : ((1u << d1) - 1u));
        c2 &= (d2 <= 0) ? 0u : ((d2 >= 32) ? ~0u : ((1u << d2) - 1u));
        c3 &= (d3 <= 0) ? 0u : ((d3 >= 32) ? ~0u : ((1u << d3) - 1u));
    }

    // rare exact path: reference fp op order, IEEE f32 division
    if (c0 | c1 | c2 | c3) {
        #pragma unroll
        for (int q = 0; q < 4; ++q) {
            uint32_t m = (q == 0) ? c0 : (q == 1) ? c1 : (q == 2) ? c2 : c3;
            if (!m) continue;
            const float4 bj = (q == 0) ? bj0 : (q == 1) ? bj1 : (q == 2) ? bj2 : bj3;
            const float ja = __fmul_rn(__fsub_rn(bj.z, bj.x), __fsub_rn(bj.w, bj.y));
            bool h = false;
            do {
                int k = __builtin_ctz(m); m &= m - 1;
                float4 bi = LB[k];
                float ia = __fmul_rn(__fsub_rn(bi.z, bi.x), __fsub_rn(bi.w, bi.y));
                float ty1 = fmaxf(bi.x, bj.x), tx1 = fmaxf(bi.y, bj.y);
                float ty2 = fminf(bi.z, bj.z), tx2 = fminf(bi.w, bj.w);
                float ih = fmaxf(__fsub_rn(ty2, ty1), 0.0f);
                float iw = fmaxf(__fsub_rn(tx2, tx1), 0.0f);
                float inter = __fmul_rn(ih, iw);
                float un = __fsub_rn(__fadd_rn(ia, ja), inter);
                float iou = inter / fmaxf(un, 1e-9f);
                h |= (iou > 0.7f);
            } while (m);
            if (h) {
                int j = jbase + q * 256 + tid;
                atomicOr(&flags[j >> 5], 1u << (j & 31));
            }
        }
    }
}

// ---------------------------------------------------------------------------
// Kernel 3: masked float4 write of sorted boxes.
// ---------------------------------------------------------------------------
__global__ __launch_bounds__(256) void nms_write_kernel(
    const float4* __restrict__ sbox, const uint32_t* __restrict__ flags,
    float4* __restrict__ out)
{
    int j = blockIdx.x * 256 + threadIdx.x;
    bool sup = (flags[j >> 5] >> (j & 31)) & 1u;
    float4 v = sbox[j];
    if (sup) { v.x = 0.0f; v.y = 0.0f; v.z = 0.0f; v.w = 0.0f; }
    out[j] = v;
}

extern "C" void kernel_launch(void* const* d_in, const int* in_sizes, int n_in,
                              void* d_out, int out_size, void* d_ws, size_t ws_size,
                              hipStream_t stream) {
    const float4* bbox  = (const float4*)d_in[0];   // (8192,4) f32
    const float*  score = (const float*)d_in[1];    // (8192,)  f32
    float4* out = (float4*)d_out;                   // (8192,4) f32
    float4* sbox = (float4*)d_ws;                   // 128 KB
    uint32_t* flags = (uint32_t*)((char*)d_ws + NBOX * 16);  // 1 KB

    hipLaunchKernelGGL(nms_rank_kernel, dim3(NBOX / 16), dim3(256), 0, stream,
                       bbox, score, sbox, flags);
    // triangular tile grid: sum_{jb=0..7} (32*jb+32) = 1152 blocks
    hipLaunchKernelGGL(nms_suppress_kernel, dim3(1152), dim3(256), 0, stream,
                       sbox, flags);
    hipLaunchKernelGGL(nms_write_kernel, dim3(NBOX / 256), dim3(256), 0, stream,
                       sbox, flags, out);
}